// Round 8
// baseline (226.062 us; speedup 1.0000x reference)
//
#include <hip/hip_runtime.h>

#define VDIM 20000
#define EDIM 128
#define BATCH 64
#define SEQ 100
#define BN 128
#define NVT 157   // ceil(20000/128)
#define AROWS 112
#define ATILE (AROWS * EDIM)   // 14336 shorts = 28 KB
#define ABYTES (ATILE * 2)     // 28672 B per buffer
#define GRID (NVT * 16)        // 2512 blocks
#define GPX (GRID / 8)         // 314 per XCD (exact)

typedef float f32x4 __attribute__((ext_vector_type(4)));
typedef float f32x2 __attribute__((ext_vector_type(2)));
typedef short bf16x8 __attribute__((ext_vector_type(8)));
typedef unsigned short ushortx8 __attribute__((ext_vector_type(8)));

typedef __attribute__((address_space(1))) const unsigned int gas_u32;
typedef __attribute__((address_space(3))) unsigned int las_u32;

__device__ __forceinline__ void async16(unsigned short* lds, const unsigned short* g) {
  __builtin_amdgcn_global_load_lds((gas_u32*)g, (las_u32*)lds, 16, 0, 0);
}

__device__ __forceinline__ unsigned short f2bf(float f) {
  unsigned u = __builtin_bit_cast(unsigned, f);
  u += 0x7FFFu + ((u >> 16) & 1u);   // RTNE
  return (unsigned short)(u >> 16);
}

// full-rate packed f32 (CDNA VOP3P); per-lane semantics identical to scalar.
// Accumulating forms use tied "+v" operands: in-place dst, NO register-pair
// copies (untied "=v" forms forced movs around every pk op — R7 lesson).
__device__ __forceinline__ f32x2 pk_mul(f32x2 a, f32x2 b) {
  f32x2 d; asm("v_pk_mul_f32 %0, %1, %2" : "=v"(d) : "v"(a), "v"(b)); return d;
}
__device__ __forceinline__ void pk_add_acc(f32x2& a, f32x2 b) {
  asm("v_pk_add_f32 %0, %0, %1" : "+v"(a) : "v"(b));
}
__device__ __forceinline__ void pk_fma_acc(f32x2& a, f32x2 m0, f32x2 m1) {
  asm("v_pk_fma_f32 %0, %1, %2, %0" : "+v"(a) : "v"(m0), "v"(m1));
}
__device__ __forceinline__ float fexp2(float x) {   // v_exp_f32: D = 2^S0
  float d; asm("v_exp_f32 %0, %1" : "=v"(d) : "v"(x)); return d;
}
#define L2E_BITS 0x3FB8AA3Bu   // RN(log2 e) — same constant __expf uses

// ---- fused prep: W->bf16 (blocks 0..2499) + A gather PRE-SWIZZLED (2500..2627)
// A tiles: 112 rows. 0..99 = W[attr], 100 = direct emb, 101..111 = zero pads.
__global__ void prep_kernel(const float* __restrict__ Wi, const float* __restrict__ Wu,
                            const int* __restrict__ attr_item, const int* __restrict__ attr_user,
                            const int* __restrict__ item_ids, const int* __restrict__ user_ids,
                            const float* __restrict__ item_emb, const float* __restrict__ user_emb,
                            unsigned short* __restrict__ wbf, unsigned short* __restrict__ abf) {
  const int bid = blockIdx.x, t = threadIdx.x;
  if (bid < 2500) {
    const int c = bid & 1;
    const float* src = c ? Wu : Wi;
    unsigned short* dst = wbf + (size_t)c * (VDIM * EDIM);
    const int i0 = ((bid >> 1) * 256 + t) * 8;
    float4 a = *(const float4*)(src + i0);
    float4 b = *(const float4*)(src + i0 + 4);
    ushortx8 o;
    o[0] = f2bf(a.x); o[1] = f2bf(a.y); o[2] = f2bf(a.z); o[3] = f2bf(a.w);
    o[4] = f2bf(b.x); o[5] = f2bf(b.y); o[6] = f2bf(b.z); o[7] = f2bf(b.w);
    *(ushortx8*)(dst + i0) = o;
  } else {
    const int g = bid - 2500;
    const int b = g & 63, c = g >> 6;
    const int r = t >> 1, h = t & 1;
    if (r >= AROWS) return;
    const int* ids = c ? attr_user : attr_item;
    const float* W = c ? Wu : Wi;
    const float* demb = c ? user_emb : item_emb;
    const int* dids = c ? user_ids : item_ids;
    unsigned short* dst = abf + (size_t)(c * BATCH + b) * ATILE;
    const float* src = nullptr;
    if (r < SEQ)       src = W + (size_t)ids[b * SEQ + r] * EDIM;
    else if (r == SEQ) src = demb + (size_t)dids[b] * EDIM;
    if (src) {
      #pragma unroll
      for (int k = 0; k < 8; ++k) {
        const int jj = h * 8 + k;
        const int j = jj ^ (r & 15);
        float4 a  = *(const float4*)(src + j * 8);
        float4 bb = *(const float4*)(src + j * 8 + 4);
        ushortx8 o;
        o[0] = f2bf(a.x);  o[1] = f2bf(a.y);  o[2] = f2bf(a.z);  o[3] = f2bf(a.w);
        o[4] = f2bf(bb.x); o[5] = f2bf(bb.y); o[6] = f2bf(bb.z); o[7] = f2bf(bb.w);
        *(ushortx8*)(dst + (r * 16 + jj) * 8) = o;
      }
    } else {
      ushortx8 z = {0, 0, 0, 0, 0, 0, 0, 0};
      #pragma unroll
      for (int k = 0; k < 8; ++k) *(ushortx8*)(dst + (r * 16 + h * 8 + k) * 8) = z;
    }
  }
}

// ---- main: 512 thr (8 waves: wm2 x wn4), tile 112 rows x 128 cols.
// Double-buffered sA, 1 barrier/stage (R7). LOAD-BALANCED (R8):
//   wm0 waves 0-3: 32 MFMA + 8 EPAIRS (heavy) -> NO combine, NO 4th DMA.
//   wm1 waves 4-7: 24 MFMA + 6 EPAIRS + 4th DMA batch; waves 6-7 run the
//   combine (t>=384, col=t&127). Every stage's barrier previously waited on
//   waves 0-1 doing combine+heavy GEMM+heavy epilogue+extra DMA.
// Tied "+v" pk accumulate ops kill the asm-interface register-pair copies.
// Numerically BIT-IDENTICAL to R5/R7 (same ops, same order; only the lane
// assignment of the combine and instruction forms changed).
__global__ __launch_bounds__(512, 4)
void main_kernel(const unsigned short* __restrict__ wbf, const unsigned short* __restrict__ abf,
                 const float* __restrict__ tf_item, const int* __restrict__ lens_item,
                 const float* __restrict__ tf_user, const int* __restrict__ lens_user,
                 float* __restrict__ out) {
  __shared__ __align__(16) unsigned short sA[2][ATILE];   // 56 KB, double-buffered
  __shared__ float sDen[2][2][BN];                        // [parity][wm][col] 4 KB
  __shared__ float sNum[2][2][BN];                        // 4 KB
  __shared__ float sDir[2][BN];                           // 1 KB
  __shared__ __align__(16) float sTF[2][4][128];          // pre-masked; 4 KB
  __shared__ float sRes[4][BN];                           // 2 KB

  const int t = threadIdx.x;
  const int bid = blockIdx.x;
  const int p = (bid & 7) * GPX + (bid >> 3);   // per-XCD sequential order
  const int v0 = (p >> 4) * BN;                 // 157 v-tiles
  const int bg4 = (p & 15) * 4;                 // 16 b-groups
  const int lane = t & 63;
  const int wave = __builtin_amdgcn_readfirstlane(t >> 6);   // SGPR (wave-uniform)
  const int wm = wave >> 2, wn = wave & 3;                    // SGPR
  const int quad = lane >> 4, l15 = lane & 15;
  const float L2E = __builtin_bit_cast(float, L2E_BITS);
  const f32x2 L2E2 = {L2E, L2E};

  // ---- stage tf into LDS, PRE-MASKED by lens (kills per-element guards) ----
  #pragma unroll
  for (int k = t; k < 1024; k += 512) {
    const int c = k >> 9, bi = (k >> 7) & 3, si = k & 127;
    const int lb = (c ? lens_user : lens_item)[bg4 + bi];
    float w = 0.f;
    if (si < lb) w = (c ? tf_user : tf_item)[(bg4 + bi) * SEQ + si];   // lb<=SEQ
    sTF[c][bi][si] = w;
  }

  // ---- B fragments for cluster 0 (32 VGPRs) ----
  bf16x8 breg[2][4];
  #pragma unroll
  for (int nt = 0; nt < 2; ++nt) {
    const int v = v0 + wn * 32 + nt * 16 + l15;
    const unsigned short* pb = wbf + (size_t)v * EDIM + quad * 8;
    const bool ok = (v < VDIM);
    #pragma unroll
    for (int ks = 0; ks < 4; ++ks) {
      bf16x8 z = {0, 0, 0, 0, 0, 0, 0, 0};
      breg[nt][ks] = ok ? *(const bf16x8*)(pb + ks * 32) : z;
    }
  }

  // ---- stage-invariant GEMM LDS base pointers (buffer 0; +ABYTES for buf1) --
  const unsigned char* pA = (const unsigned char*)&sA[0][0];
  const int rowb = (wm * 64 + l15) * 256;
  const unsigned char* aB0 = pA + rowb + (((0 * 4 + quad) ^ l15) << 4);
  const unsigned char* aB1 = pA + rowb + (((1 * 4 + quad) ^ l15) << 4);
  const unsigned char* aB2 = pA + rowb + (((2 * 4 + quad) ^ l15) << 4);
  const unsigned char* aB3 = pA + rowb + (((3 * 4 + quad) ^ l15) << 4);

  // ---- issue async A DMA for stage 0 into buf0 (tail on light wm1 waves) ---
  {
    const unsigned short* gb = abf + (size_t)bg4 * ATILE;
    #pragma unroll
    for (int i = 0; i < 3; ++i)
      async16(&sA[0][(i * 512 + wave * 64) * 8], gb + (size_t)(i * 512 + t) * 8);
    if (t >= 256)   // waves 4..7 cover shorts 12288..14335
      async16(&sA[0][(1536 + (wave - 4) * 64) * 8], gb + (size_t)(1536 + (t - 256)) * 8);
  }

  #pragma unroll 1
  for (int s = 0; s < 8; ++s) {
    const int cc = s >> 2, it = s & 3, buf = s & 1;

    __syncthreads();   // DMA for buf[s&1] drained; s-1 partials visible;
                       // buf[(s+1)&1] free (its last readers were pre-barrier)

    // ---- issue next stage's DMA into the other buffer (full-stage flight) --
    if (s < 7) {
      const int ns = s + 1;
      unsigned short* db = &sA[ns & 1][0];
      const unsigned short* gb = abf + (size_t)((ns >> 2) * BATCH + bg4 + (ns & 3)) * ATILE;
      #pragma unroll
      for (int i = 0; i < 3; ++i)
        async16(db + (size_t)(i * 512 + wave * 64) * 8, gb + (size_t)(i * 512 + t) * 8);
      if (t >= 256)
        async16(db + (size_t)(1536 + (wave - 4) * 64) * 8, gb + (size_t)(1536 + (t - 256)) * 8);
    }

    // ---- combine previous stage's partials — waves 6-7 (light wm1 side) ----
    if (s > 0 && t >= 384) {
      const int col = t & 127;   // 384..511 -> 0..127
      const int ps = s - 1, pp = ps & 1, pit = ps & 3;
      float den = sDen[pp][0][col] + sDen[pp][1][col];
      float num = sNum[pp][0][col] + sNum[pp][1][col];
      const float dir = sDir[pp][col];
      const float dirE = fexp2(dir * L2E);       // same path as epilogue's den term
      den -= 11.f + dirE;                        // 11 pad rows (101..111) + dir row
      const float val = num * __builtin_amdgcn_rcpf(den) + dir;
      if (ps < 4) sRes[pit][col] = val;
      else {
        const int v = v0 + col;
        if (v < VDIM) out[(size_t)(bg4 + pit) * VDIM + v] = sRes[pit][col] + val;
      }
    }

    // ---- GEMM: 16x16x32 tiles; A from LDS (hoisted bases + imm offsets) ----
    f32x4 acc[4][2];
    #pragma unroll
    for (int mt = 0; mt < 4; ++mt)
      #pragma unroll
      for (int nt = 0; nt < 2; ++nt) { f32x4 z = {0.f, 0.f, 0.f, 0.f}; acc[mt][nt] = z; }

    const int bufB = buf * ABYTES;
    #pragma unroll
    for (int ks = 0; ks < 4; ++ks) {
      const unsigned char* ab =
          ((ks == 0) ? aB0 : (ks == 1) ? aB1 : (ks == 2) ? aB2 : aB3) + bufB;
      #pragma unroll
      for (int mt = 0; mt < 3; ++mt) {   // JIT af: 4 live regs, not 12
        const bf16x8 a = *(const bf16x8*)(ab + mt * 4096);
        acc[mt][0] = __builtin_amdgcn_mfma_f32_16x16x32_bf16(a, breg[0][ks], acc[mt][0], 0, 0, 0);
        acc[mt][1] = __builtin_amdgcn_mfma_f32_16x16x32_bf16(a, breg[1][ks], acc[mt][1], 0, 0, 0);
      }
      if (wm == 0) {   // SGPR-uniform (SCC branch); rows 48..63
        const bf16x8 a3 = *(const bf16x8*)(ab + 3 * 4096);
        acc[3][0] = __builtin_amdgcn_mfma_f32_16x16x32_bf16(a3, breg[0][ks], acc[3][0], 0, 0, 0);
        acc[3][1] = __builtin_amdgcn_mfma_f32_16x16x32_bf16(a3, breg[1][ks], acc[3][1], 0, 0, 0);
      }
    }

    // reload B for cluster 1 once (covered by epilogue; drained at next sync)
    if (s == 3) {
      const unsigned short* wb1 = wbf + (size_t)VDIM * EDIM;
      #pragma unroll
      for (int nt = 0; nt < 2; ++nt) {
        const int v = v0 + wn * 32 + nt * 16 + l15;
        const unsigned short* pb = wb1 + (size_t)v * EDIM + quad * 8;
        const bool ok = (v < VDIM);
        #pragma unroll
        for (int ks = 0; ks < 4; ++ks) {
          bf16x8 z = {0, 0, 0, 0, 0, 0, 0, 0};
          breg[nt][ks] = ok ? *(const bf16x8*)(pb + ks * 32) : z;
        }
      }
    }

    // ---- epilogue: packed-f32 softmax partials (identical math to R5) ----
    f32x2 wlo[4], whi[4];
    #pragma unroll
    for (int mt = 0; mt < 4; ++mt) {
      const int row0 = wm * 64 + mt * 16 + quad * 4;   // <=124 < 128, pad region is 0
      const f32x4 w4 = *(const f32x4*)&sTF[cc][it][row0];
      f32x2 a = {w4[0], w4[1]}; f32x2 b = {w4[2], w4[3]};
      wlo[mt] = a; whi[mt] = b;
    }

    #pragma unroll
    for (int nt = 0; nt < 2; ++nt) {
      f32x2 den2 = {0.f, 0.f}, num2 = {0.f, 0.f};

      #define EPAIRS(MT)                                                  \
      {                                                                   \
        const f32x4 a4 = acc[MT][nt];                                     \
        const f32x2 vlo = {a4[0], a4[1]};                                 \
        const f32x2 vhi = {a4[2], a4[3]};                                 \
        const f32x2 mlo = pk_mul(vlo, L2E2);                              \
        const f32x2 mhi = pk_mul(vhi, L2E2);                              \
        f32x2 elo, ehi;                                                   \
        elo[0] = fexp2(mlo[0]); elo[1] = fexp2(mlo[1]);                   \
        ehi[0] = fexp2(mhi[0]); ehi[1] = fexp2(mhi[1]);                   \
        pk_add_acc(den2, elo);                                            \
        pk_add_acc(den2, ehi);                                            \
        pk_fma_acc(num2, wlo[MT], pk_mul(elo, vlo));                      \
        pk_fma_acc(num2, whi[MT], pk_mul(ehi, vhi));                      \
      }
      EPAIRS(0)
      EPAIRS(1)
      EPAIRS(2)
      if (wm == 0) EPAIRS(3)   // SGPR-uniform; static acc[3][nt]
      #undef EPAIRS

      float den = den2[0] + den2[1];
      float num = num2[0] + num2[1];
      den += __shfl_xor(den, 16, 64);
      den += __shfl_xor(den, 32, 64);
      num += __shfl_xor(num, 16, 64);
      num += __shfl_xor(num, 32, 64);
      const int col = wn * 32 + nt * 16 + l15;
      if (quad == 0) {
        sDen[buf][wm][col] = den;
        sNum[buf][wm][col] = num;
      }
      // row 100 = wm1, mt2, quad1, r0
      if (wm == 1 && quad == 1) sDir[buf][col] = acc[2][nt][0];
    }
  }

  __syncthreads();

  // ---- combine final stage (ps=7, parity 1, it=3) — waves 6-7 ----
  if (t >= 384) {
    const int col = t & 127;
    float den = sDen[1][0][col] + sDen[1][1][col];
    float num = sNum[1][0][col] + sNum[1][1][col];
    const float dir = sDir[1][col];
    const float dirE = fexp2(dir * L2E);
    den -= 11.f + dirE;
    const float val = num * __builtin_amdgcn_rcpf(den) + dir;
    const int v = v0 + col;
    if (v < VDIM) out[(size_t)(bg4 + 3) * VDIM + v] = sRes[3][col] + val;
  }
}

extern "C" void kernel_launch(void* const* d_in, const int* in_sizes, int n_in,
                              void* d_out, int out_size, void* d_ws, size_t ws_size,
                              hipStream_t stream) {
  const int*   attr_item = (const int*)d_in[0];
  const float* tf_item   = (const float*)d_in[1];
  const int*   lens_item = (const int*)d_in[2];
  const int*   item_ids  = (const int*)d_in[3];
  const int*   attr_user = (const int*)d_in[4];
  const float* tf_user   = (const float*)d_in[5];
  const int*   lens_user = (const int*)d_in[6];
  const int*   user_ids  = (const int*)d_in[7];
  const float* W_item    = (const float*)d_in[8];
  const float* W_user    = (const float*)d_in[9];
  const float* user_emb  = (const float*)d_in[10];
  const float* item_emb  = (const float*)d_in[11];
  float* out = (float*)d_out;

  unsigned short* wbf = (unsigned short*)d_ws;                  // [2][V][E] bf16 (linear)
  unsigned short* abf = wbf + (size_t)2 * VDIM * EDIM;          // [2][64] swizzled 28KB tiles

  prep_kernel<<<dim3(2500 + 128), 256, 0, stream>>>(W_item, W_user, attr_item, attr_user,
                                                    item_ids, user_ids, item_emb, user_emb,
                                                    wbf, abf);
  main_kernel<<<dim3(GRID), 512, 0, stream>>>(wbf, abf, tf_item, lens_item,
                                              tf_user, lens_user, out);
}

// Round 9
// 221.543 us; speedup vs baseline: 1.0204x; 1.0204x over previous
//
#include <hip/hip_runtime.h>

#define VDIM 20000
#define EDIM 128
#define BATCH 64
#define SEQ 100
#define BN 128
#define NVT 157   // ceil(20000/128)
#define AROWS 112
#define ATILE (AROWS * EDIM)   // 14336 shorts = 28 KB
#define ABYTES (ATILE * 2)     // 28672 B per buffer
#define GRID (NVT * 16)        // 2512 blocks
#define GPX (GRID / 8)         // 314 per XCD (exact)

typedef float f32x4 __attribute__((ext_vector_type(4)));
typedef float f32x2 __attribute__((ext_vector_type(2)));
typedef short bf16x8 __attribute__((ext_vector_type(8)));
typedef unsigned short ushortx8 __attribute__((ext_vector_type(8)));

typedef __attribute__((address_space(1))) const unsigned int gas_u32;
typedef __attribute__((address_space(3))) unsigned int las_u32;

__device__ __forceinline__ void async16(unsigned short* lds, const unsigned short* g) {
  __builtin_amdgcn_global_load_lds((gas_u32*)g, (las_u32*)lds, 16, 0, 0);
}

__device__ __forceinline__ unsigned short f2bf(float f) {
  unsigned u = __builtin_bit_cast(unsigned, f);
  u += 0x7FFFu + ((u >> 16) & 1u);   // RTNE
  return (unsigned short)(u >> 16);
}

// full-rate packed f32 (CDNA VOP3P); per-lane semantics identical to scalar.
__device__ __forceinline__ f32x2 pk_mul(f32x2 a, f32x2 b) {
  f32x2 d; asm("v_pk_mul_f32 %0, %1, %2" : "=v"(d) : "v"(a), "v"(b)); return d;
}
__device__ __forceinline__ void pk_add_acc(f32x2& a, f32x2 b) {
  asm("v_pk_add_f32 %0, %0, %1" : "+v"(a) : "v"(b));
}
__device__ __forceinline__ void pk_fma_acc(f32x2& a, f32x2 m0, f32x2 m1) {
  asm("v_pk_fma_f32 %0, %1, %2, %0" : "+v"(a) : "v"(m0), "v"(m1));
}
__device__ __forceinline__ float fexp2(float x) {   // v_exp_f32: D = 2^S0
  float d; asm("v_exp_f32 %0, %1" : "=v"(d) : "v"(x)); return d;
}
#define L2E_BITS 0x3FB8AA3Bu   // RN(log2 e) — same constant __expf uses

// ---- fused prep: W->bf16 (blocks 0..2499) + A gather PRE-SWIZZLED (2500..2627)
// A tiles: 112 rows. 0..99 = W[attr], 100 = direct emb, 101..111 = zero pads.
__global__ void prep_kernel(const float* __restrict__ Wi, const float* __restrict__ Wu,
                            const int* __restrict__ attr_item, const int* __restrict__ attr_user,
                            const int* __restrict__ item_ids, const int* __restrict__ user_ids,
                            const float* __restrict__ item_emb, const float* __restrict__ user_emb,
                            unsigned short* __restrict__ wbf, unsigned short* __restrict__ abf) {
  const int bid = blockIdx.x, t = threadIdx.x;
  if (bid < 2500) {
    const int c = bid & 1;
    const float* src = c ? Wu : Wi;
    unsigned short* dst = wbf + (size_t)c * (VDIM * EDIM);
    const int i0 = ((bid >> 1) * 256 + t) * 8;
    float4 a = *(const float4*)(src + i0);
    float4 b = *(const float4*)(src + i0 + 4);
    ushortx8 o;
    o[0] = f2bf(a.x); o[1] = f2bf(a.y); o[2] = f2bf(a.z); o[3] = f2bf(a.w);
    o[4] = f2bf(b.x); o[5] = f2bf(b.y); o[6] = f2bf(b.z); o[7] = f2bf(b.w);
    *(ushortx8*)(dst + i0) = o;
  } else {
    const int g = bid - 2500;
    const int b = g & 63, c = g >> 6;
    const int r = t >> 1, h = t & 1;
    if (r >= AROWS) return;
    const int* ids = c ? attr_user : attr_item;
    const float* W = c ? Wu : Wi;
    const float* demb = c ? user_emb : item_emb;
    const int* dids = c ? user_ids : item_ids;
    unsigned short* dst = abf + (size_t)(c * BATCH + b) * ATILE;
    const float* src = nullptr;
    if (r < SEQ)       src = W + (size_t)ids[b * SEQ + r] * EDIM;
    else if (r == SEQ) src = demb + (size_t)dids[b] * EDIM;
    if (src) {
      #pragma unroll
      for (int k = 0; k < 8; ++k) {
        const int jj = h * 8 + k;
        const int j = jj ^ (r & 15);
        float4 a  = *(const float4*)(src + j * 8);
        float4 bb = *(const float4*)(src + j * 8 + 4);
        ushortx8 o;
        o[0] = f2bf(a.x);  o[1] = f2bf(a.y);  o[2] = f2bf(a.z);  o[3] = f2bf(a.w);
        o[4] = f2bf(bb.x); o[5] = f2bf(bb.y); o[6] = f2bf(bb.z); o[7] = f2bf(bb.w);
        *(ushortx8*)(dst + (r * 16 + jj) * 8) = o;
      }
    } else {
      ushortx8 z = {0, 0, 0, 0, 0, 0, 0, 0};
      #pragma unroll
      for (int k = 0; k < 8; ++k) *(ushortx8*)(dst + (r * 16 + h * 8 + k) * 8) = z;
    }
  }
}

// ---- main: 512 thr (8 waves: wm2 x wn4), tile 112 rows x 128 cols.
// Double-buffered sA, 1 barrier/stage, load-balanced (R8). R9 cuts:
//  (1) zero4-seeded ks0 MFMA — no 32-reg acc zero-init per stage (MFMA is
//      exact accumulate => bit-identical).
//  (2) reduction: single shfl_xor(16) + quad-pair partials in LDS; combine
//      sums (qp0+qp1)_wm0 + (qp0+qp1)_wm1 — same associativity as the old
//      xor16->xor32->wm chain => bit-identical. -4 bpermutes + -2 dependent
//      lgkm chains per wave-stage; LDS 68.6->72.7 KB (still 2 blocks/CU).
__global__ __launch_bounds__(512, 4)
void main_kernel(const unsigned short* __restrict__ wbf, const unsigned short* __restrict__ abf,
                 const float* __restrict__ tf_item, const int* __restrict__ lens_item,
                 const float* __restrict__ tf_user, const int* __restrict__ lens_user,
                 float* __restrict__ out) {
  __shared__ __align__(16) unsigned short sA[2][ATILE];   // 56 KB, double-buffered
  __shared__ float sDen[2][2][2][BN];                     // [parity][wm][qpair][col] 4 KB
  __shared__ float sNum[2][2][2][BN];                     // 4 KB
  __shared__ float sDir[2][BN];                           // 1 KB
  __shared__ __align__(16) float sTF[2][4][128];          // pre-masked; 4 KB
  __shared__ float sRes[4][BN];                           // 2 KB

  const int t = threadIdx.x;
  const int bid = blockIdx.x;
  const int p = (bid & 7) * GPX + (bid >> 3);   // per-XCD sequential order
  const int v0 = (p >> 4) * BN;                 // 157 v-tiles
  const int bg4 = (p & 15) * 4;                 // 16 b-groups
  const int lane = t & 63;
  const int wave = __builtin_amdgcn_readfirstlane(t >> 6);   // SGPR (wave-uniform)
  const int wm = wave >> 2, wn = wave & 3;                    // SGPR
  const int quad = lane >> 4, l15 = lane & 15;
  const float L2E = __builtin_bit_cast(float, L2E_BITS);
  const f32x2 L2E2 = {L2E, L2E};

  // ---- stage tf into LDS, PRE-MASKED by lens (kills per-element guards) ----
  #pragma unroll
  for (int k = t; k < 1024; k += 512) {
    const int c = k >> 9, bi = (k >> 7) & 3, si = k & 127;
    const int lb = (c ? lens_user : lens_item)[bg4 + bi];
    float w = 0.f;
    if (si < lb) w = (c ? tf_user : tf_item)[(bg4 + bi) * SEQ + si];   // lb<=SEQ
    sTF[c][bi][si] = w;
  }

  // ---- B fragments for cluster 0 (32 VGPRs) ----
  bf16x8 breg[2][4];
  #pragma unroll
  for (int nt = 0; nt < 2; ++nt) {
    const int v = v0 + wn * 32 + nt * 16 + l15;
    const unsigned short* pb = wbf + (size_t)v * EDIM + quad * 8;
    const bool ok = (v < VDIM);
    #pragma unroll
    for (int ks = 0; ks < 4; ++ks) {
      bf16x8 z = {0, 0, 0, 0, 0, 0, 0, 0};
      breg[nt][ks] = ok ? *(const bf16x8*)(pb + ks * 32) : z;
    }
  }

  // ---- stage-invariant GEMM LDS base pointers (buffer 0; +ABYTES for buf1) --
  const unsigned char* pA = (const unsigned char*)&sA[0][0];
  const int rowb = (wm * 64 + l15) * 256;
  const unsigned char* aB0 = pA + rowb + (((0 * 4 + quad) ^ l15) << 4);
  const unsigned char* aB1 = pA + rowb + (((1 * 4 + quad) ^ l15) << 4);
  const unsigned char* aB2 = pA + rowb + (((2 * 4 + quad) ^ l15) << 4);
  const unsigned char* aB3 = pA + rowb + (((3 * 4 + quad) ^ l15) << 4);

  // persistent zero C-operand (4 VGPRs) — replaces per-stage acc zero-init
  f32x4 zero4 = {0.f, 0.f, 0.f, 0.f};

  // ---- issue async A DMA for stage 0 into buf0 (tail on light wm1 waves) ---
  {
    const unsigned short* gb = abf + (size_t)bg4 * ATILE;
    #pragma unroll
    for (int i = 0; i < 3; ++i)
      async16(&sA[0][(i * 512 + wave * 64) * 8], gb + (size_t)(i * 512 + t) * 8);
    if (t >= 256)   // waves 4..7 cover shorts 12288..14335
      async16(&sA[0][(1536 + (wave - 4) * 64) * 8], gb + (size_t)(1536 + (t - 256)) * 8);
  }

  #pragma unroll 1
  for (int s = 0; s < 8; ++s) {
    const int cc = s >> 2, it = s & 3, buf = s & 1;

    __syncthreads();   // DMA for buf[s&1] drained; s-1 partials visible;
                       // buf[(s+1)&1] free (its last readers were pre-barrier)

    // ---- issue next stage's DMA into the other buffer (full-stage flight) --
    if (s < 7) {
      const int ns = s + 1;
      unsigned short* db = &sA[ns & 1][0];
      const unsigned short* gb = abf + (size_t)((ns >> 2) * BATCH + bg4 + (ns & 3)) * ATILE;
      #pragma unroll
      for (int i = 0; i < 3; ++i)
        async16(db + (size_t)(i * 512 + wave * 64) * 8, gb + (size_t)(i * 512 + t) * 8);
      if (t >= 256)
        async16(db + (size_t)(1536 + (wave - 4) * 64) * 8, gb + (size_t)(1536 + (t - 256)) * 8);
    }

    // ---- combine previous stage's partials — waves 6-7 (light wm1 side) ----
    if (s > 0 && t >= 384) {
      const int col = t & 127;   // 384..511 -> 0..127
      const int ps = s - 1, pp = ps & 1, pit = ps & 3;
      // same associativity as old xor16->xor32->wm-sum chain:
      const float den0 = sDen[pp][0][0][col] + sDen[pp][0][1][col];
      const float den1 = sDen[pp][1][0][col] + sDen[pp][1][1][col];
      const float num0 = sNum[pp][0][0][col] + sNum[pp][0][1][col];
      const float num1 = sNum[pp][1][0][col] + sNum[pp][1][1][col];
      float den = den0 + den1;
      float num = num0 + num1;
      const float dir = sDir[pp][col];
      const float dirE = fexp2(dir * L2E);       // same path as epilogue's den term
      den -= 11.f + dirE;                        // 11 pad rows (101..111) + dir row
      const float val = num * __builtin_amdgcn_rcpf(den) + dir;
      if (ps < 4) sRes[pit][col] = val;
      else {
        const int v = v0 + col;
        if (v < VDIM) out[(size_t)(bg4 + pit) * VDIM + v] = sRes[pit][col] + val;
      }
    }

    // ---- GEMM: 16x16x32 tiles; ks0 seeds from zero4 (no acc init) ----
    f32x4 acc[4][2];
    const int bufB = buf * ABYTES;
    #pragma unroll
    for (int ks = 0; ks < 4; ++ks) {
      const unsigned char* ab =
          ((ks == 0) ? aB0 : (ks == 1) ? aB1 : (ks == 2) ? aB2 : aB3) + bufB;
      #pragma unroll
      for (int mt = 0; mt < 3; ++mt) {   // JIT af: 4 live regs
        const bf16x8 a = *(const bf16x8*)(ab + mt * 4096);
        if (ks == 0) {
          acc[mt][0] = __builtin_amdgcn_mfma_f32_16x16x32_bf16(a, breg[0][0], zero4, 0, 0, 0);
          acc[mt][1] = __builtin_amdgcn_mfma_f32_16x16x32_bf16(a, breg[1][0], zero4, 0, 0, 0);
        } else {
          acc[mt][0] = __builtin_amdgcn_mfma_f32_16x16x32_bf16(a, breg[0][ks], acc[mt][0], 0, 0, 0);
          acc[mt][1] = __builtin_amdgcn_mfma_f32_16x16x32_bf16(a, breg[1][ks], acc[mt][1], 0, 0, 0);
        }
      }
      if (wm == 0) {   // SGPR-uniform (SCC branch); rows 48..63
        const bf16x8 a3 = *(const bf16x8*)(ab + 3 * 4096);
        if (ks == 0) {
          acc[3][0] = __builtin_amdgcn_mfma_f32_16x16x32_bf16(a3, breg[0][0], zero4, 0, 0, 0);
          acc[3][1] = __builtin_amdgcn_mfma_f32_16x16x32_bf16(a3, breg[1][0], zero4, 0, 0, 0);
        } else {
          acc[3][0] = __builtin_amdgcn_mfma_f32_16x16x32_bf16(a3, breg[0][ks], acc[3][0], 0, 0, 0);
          acc[3][1] = __builtin_amdgcn_mfma_f32_16x16x32_bf16(a3, breg[1][ks], acc[3][1], 0, 0, 0);
        }
      }
    }

    // reload B for cluster 1 once (covered by epilogue; drained at next sync)
    if (s == 3) {
      const unsigned short* wb1 = wbf + (size_t)VDIM * EDIM;
      #pragma unroll
      for (int nt = 0; nt < 2; ++nt) {
        const int v = v0 + wn * 32 + nt * 16 + l15;
        const unsigned short* pb = wb1 + (size_t)v * EDIM + quad * 8;
        const bool ok = (v < VDIM);
        #pragma unroll
        for (int ks = 0; ks < 4; ++ks) {
          bf16x8 z = {0, 0, 0, 0, 0, 0, 0, 0};
          breg[nt][ks] = ok ? *(const bf16x8*)(pb + ks * 32) : z;
        }
      }
    }

    // ---- epilogue: packed-f32 softmax partials (identical math to R5) ----
    f32x2 wlo[4], whi[4];
    #pragma unroll
    for (int mt = 0; mt < 4; ++mt) {
      const int row0 = wm * 64 + mt * 16 + quad * 4;   // <=124 < 128, pad region is 0
      const f32x4 w4 = *(const f32x4*)&sTF[cc][it][row0];
      f32x2 a = {w4[0], w4[1]}; f32x2 b = {w4[2], w4[3]};
      wlo[mt] = a; whi[mt] = b;
    }

    #pragma unroll
    for (int nt = 0; nt < 2; ++nt) {
      f32x2 den2 = {0.f, 0.f}, num2 = {0.f, 0.f};

      #define EPAIRS(MT)                                                  \
      {                                                                   \
        const f32x4 a4 = acc[MT][nt];                                     \
        const f32x2 vlo = {a4[0], a4[1]};                                 \
        const f32x2 vhi = {a4[2], a4[3]};                                 \
        const f32x2 mlo = pk_mul(vlo, L2E2);                              \
        const f32x2 mhi = pk_mul(vhi, L2E2);                              \
        f32x2 elo, ehi;                                                   \
        elo[0] = fexp2(mlo[0]); elo[1] = fexp2(mlo[1]);                   \
        ehi[0] = fexp2(mhi[0]); ehi[1] = fexp2(mhi[1]);                   \
        pk_add_acc(den2, elo);                                            \
        pk_add_acc(den2, ehi);                                            \
        pk_fma_acc(num2, wlo[MT], pk_mul(elo, vlo));                      \
        pk_fma_acc(num2, whi[MT], pk_mul(ehi, vhi));                      \
      }
      EPAIRS(0)
      EPAIRS(1)
      EPAIRS(2)
      if (wm == 0) EPAIRS(3)   // SGPR-uniform; static acc[3][nt]
      #undef EPAIRS

      float den = den2[0] + den2[1];
      float num = num2[0] + num2[1];
      // single xor16: quads {0,1} hold q0+q1, quads {2,3} hold q2+q3
      den += __shfl_xor(den, 16, 64);
      num += __shfl_xor(num, 16, 64);
      const int col = wn * 32 + nt * 16 + l15;
      if ((quad & 1) == 0) {           // quads 0 and 2 write their pair-sum
        const int qp = quad >> 1;
        sDen[buf][wm][qp][col] = den;
        sNum[buf][wm][qp][col] = num;
      }
      // row 100 = wm1, mt2, quad1, r0
      if (wm == 1 && quad == 1) sDir[buf][col] = acc[2][nt][0];
    }
  }

  __syncthreads();

  // ---- combine final stage (ps=7, parity 1, it=3) — waves 6-7 ----
  if (t >= 384) {
    const int col = t & 127;
    const float den0 = sDen[1][0][0][col] + sDen[1][0][1][col];
    const float den1 = sDen[1][1][0][col] + sDen[1][1][1][col];
    const float num0 = sNum[1][0][0][col] + sNum[1][0][1][col];
    const float num1 = sNum[1][1][0][col] + sNum[1][1][1][col];
    float den = den0 + den1;
    float num = num0 + num1;
    const float dir = sDir[1][col];
    const float dirE = fexp2(dir * L2E);
    den -= 11.f + dirE;
    const float val = num * __builtin_amdgcn_rcpf(den) + dir;
    const int v = v0 + col;
    if (v < VDIM) out[(size_t)(bg4 + 3) * VDIM + v] = sRes[3][col] + val;
  }
}

extern "C" void kernel_launch(void* const* d_in, const int* in_sizes, int n_in,
                              void* d_out, int out_size, void* d_ws, size_t ws_size,
                              hipStream_t stream) {
  const int*   attr_item = (const int*)d_in[0];
  const float* tf_item   = (const float*)d_in[1];
  const int*   lens_item = (const int*)d_in[2];
  const int*   item_ids  = (const int*)d_in[3];
  const int*   attr_user = (const int*)d_in[4];
  const float* tf_user   = (const float*)d_in[5];
  const int*   lens_user = (const int*)d_in[6];
  const int*   user_ids  = (const int*)d_in[7];
  const float* W_item    = (const float*)d_in[8];
  const float* W_user    = (const float*)d_in[9];
  const float* user_emb  = (const float*)d_in[10];
  const float* item_emb  = (const float*)d_in[11];
  float* out = (float*)d_out;

  unsigned short* wbf = (unsigned short*)d_ws;                  // [2][V][E] bf16 (linear)
  unsigned short* abf = wbf + (size_t)2 * VDIM * EDIM;          // [2][64] swizzled 28KB tiles

  prep_kernel<<<dim3(2500 + 128), 256, 0, stream>>>(W_item, W_user, attr_item, attr_user,
                                                    item_ids, user_ids, item_emb, user_emb,
                                                    wbf, abf);
  main_kernel<<<dim3(GRID), 512, 0, stream>>>(wbf, abf, tf_item, lens_item,
                                              tf_user, lens_user, out);
}

// Round 10
// 217.785 us; speedup vs baseline: 1.0380x; 1.0173x over previous
//
#include <hip/hip_runtime.h>

#define VDIM 20000
#define EDIM 128
#define BATCH 64
#define SEQ 100
#define BN 128
#define NVT 157   // ceil(20000/128)
#define AROWS 112
#define ATILE (AROWS * EDIM)   // 14336 shorts = 28 KB
#define ABYTES (ATILE * 2)     // 28672 B per buffer
#define GRID (NVT * 16)        // 2512 blocks
#define GPX (GRID / 8)         // 314 per XCD (exact)

typedef float f32x4 __attribute__((ext_vector_type(4)));
typedef float f32x2 __attribute__((ext_vector_type(2)));
typedef short bf16x8 __attribute__((ext_vector_type(8)));
typedef unsigned short ushortx8 __attribute__((ext_vector_type(8)));

typedef __attribute__((address_space(1))) const unsigned int gas_u32;
typedef __attribute__((address_space(3))) unsigned int las_u32;

__device__ __forceinline__ void async16(unsigned short* lds, const unsigned short* g) {
  __builtin_amdgcn_global_load_lds((gas_u32*)g, (las_u32*)lds, 16, 0, 0);
}

__device__ __forceinline__ unsigned short f2bf(float f) {
  unsigned u = __builtin_bit_cast(unsigned, f);
  u += 0x7FFFu + ((u >> 16) & 1u);   // RTNE
  return (unsigned short)(u >> 16);
}

// full-rate packed f32 (CDNA VOP3P); per-lane semantics identical to scalar.
__device__ __forceinline__ f32x2 pk_mul(f32x2 a, f32x2 b) {
  f32x2 d; asm("v_pk_mul_f32 %0, %1, %2" : "=v"(d) : "v"(a), "v"(b)); return d;
}
__device__ __forceinline__ void pk_add_acc(f32x2& a, f32x2 b) {
  asm("v_pk_add_f32 %0, %0, %1" : "+v"(a) : "v"(b));
}
__device__ __forceinline__ void pk_fma_acc(f32x2& a, f32x2 m0, f32x2 m1) {
  asm("v_pk_fma_f32 %0, %1, %2, %0" : "+v"(a) : "v"(m0), "v"(m1));
}
__device__ __forceinline__ float fexp2(float x) {   // v_exp_f32: D = 2^S0
  float d; asm("v_exp_f32 %0, %1" : "=v"(d) : "v"(x)); return d;
}
#define L2E_BITS 0x3FB8AA3Bu   // RN(log2 e) — same constant __expf uses

// ---- fused prep: W->bf16 (blocks 0..2499) + A gather PRE-SWIZZLED (2500..2627)
// A tiles: 112 rows. 0..99 = W[attr], 100 = direct emb, 101..111 = zero pads.
__global__ void prep_kernel(const float* __restrict__ Wi, const float* __restrict__ Wu,
                            const int* __restrict__ attr_item, const int* __restrict__ attr_user,
                            const int* __restrict__ item_ids, const int* __restrict__ user_ids,
                            const float* __restrict__ item_emb, const float* __restrict__ user_emb,
                            unsigned short* __restrict__ wbf, unsigned short* __restrict__ abf) {
  const int bid = blockIdx.x, t = threadIdx.x;
  if (bid < 2500) {
    const int c = bid & 1;
    const float* src = c ? Wu : Wi;
    unsigned short* dst = wbf + (size_t)c * (VDIM * EDIM);
    const int i0 = ((bid >> 1) * 256 + t) * 8;
    float4 a = *(const float4*)(src + i0);
    float4 b = *(const float4*)(src + i0 + 4);
    ushortx8 o;
    o[0] = f2bf(a.x); o[1] = f2bf(a.y); o[2] = f2bf(a.z); o[3] = f2bf(a.w);
    o[4] = f2bf(b.x); o[5] = f2bf(b.y); o[6] = f2bf(b.z); o[7] = f2bf(b.w);
    *(ushortx8*)(dst + i0) = o;
  } else {
    const int g = bid - 2500;
    const int b = g & 63, c = g >> 6;
    const int r = t >> 1, h = t & 1;
    if (r >= AROWS) return;
    const int* ids = c ? attr_user : attr_item;
    const float* W = c ? Wu : Wi;
    const float* demb = c ? user_emb : item_emb;
    const int* dids = c ? user_ids : item_ids;
    unsigned short* dst = abf + (size_t)(c * BATCH + b) * ATILE;
    const float* src = nullptr;
    if (r < SEQ)       src = W + (size_t)ids[b * SEQ + r] * EDIM;
    else if (r == SEQ) src = demb + (size_t)dids[b] * EDIM;
    if (src) {
      #pragma unroll
      for (int k = 0; k < 8; ++k) {
        const int jj = h * 8 + k;
        const int j = jj ^ (r & 15);
        float4 a  = *(const float4*)(src + j * 8);
        float4 bb = *(const float4*)(src + j * 8 + 4);
        ushortx8 o;
        o[0] = f2bf(a.x);  o[1] = f2bf(a.y);  o[2] = f2bf(a.z);  o[3] = f2bf(a.w);
        o[4] = f2bf(bb.x); o[5] = f2bf(bb.y); o[6] = f2bf(bb.z); o[7] = f2bf(bb.w);
        *(ushortx8*)(dst + (r * 16 + jj) * 8) = o;
      }
    } else {
      ushortx8 z = {0, 0, 0, 0, 0, 0, 0, 0};
      #pragma unroll
      for (int k = 0; k < 8; ++k) *(ushortx8*)(dst + (r * 16 + h * 8 + k) * 8) = z;
    }
  }
}

// ---- main: 512 thr (8 waves: wm2 x wn4), tile 112 rows x 128 cols.
// Double-buffered sA, 1 barrier/stage, load-balanced, zero4-seeded MFMA (R9).
// R10 cuts:
//  (1) ZERO-SHUFFLE reduction: each quad writes its partial P(q) directly to
//      sDen/sNum[parity][wm][quad][col]; combine computes
//      ((P0+P1)+(P2+P3))_wm0 + (...)_wm1 — the EXACT association of the old
//      xor16->pair->combine tree => bit-identical. -4 ds_bpermute -2
//      dependent lgkm chains per thread-stage. LDS 72.7->80.9 KB (<=80KB/2
//      blocks boundary: 80896 <= 81920, still 2 blocks/CU).
//  (2) s_setprio(1) around the MFMA cluster (T5): the 2 resident blocks run
//      in anti-phase (one GEMM, one epilogue) — priority lets MFMA waves
//      preempt the other block's epilogue VALU issue.
__global__ __launch_bounds__(512, 4)
void main_kernel(const unsigned short* __restrict__ wbf, const unsigned short* __restrict__ abf,
                 const float* __restrict__ tf_item, const int* __restrict__ lens_item,
                 const float* __restrict__ tf_user, const int* __restrict__ lens_user,
                 float* __restrict__ out) {
  __shared__ __align__(16) unsigned short sA[2][ATILE];   // 56 KB, double-buffered
  __shared__ float sDen[2][2][4][BN];                     // [parity][wm][quad][col] 8 KB
  __shared__ float sNum[2][2][4][BN];                     // 8 KB
  __shared__ float sDir[2][BN];                           // 1 KB
  __shared__ __align__(16) float sTF[2][4][128];          // pre-masked; 4 KB
  __shared__ float sRes[4][BN];                           // 2 KB

  const int t = threadIdx.x;
  const int bid = blockIdx.x;
  const int p = (bid & 7) * GPX + (bid >> 3);   // per-XCD sequential order
  const int v0 = (p >> 4) * BN;                 // 157 v-tiles
  const int bg4 = (p & 15) * 4;                 // 16 b-groups
  const int lane = t & 63;
  const int wave = __builtin_amdgcn_readfirstlane(t >> 6);   // SGPR (wave-uniform)
  const int wm = wave >> 2, wn = wave & 3;                    // SGPR
  const int quad = lane >> 4, l15 = lane & 15;
  const float L2E = __builtin_bit_cast(float, L2E_BITS);
  const f32x2 L2E2 = {L2E, L2E};

  // ---- stage tf into LDS, PRE-MASKED by lens (kills per-element guards) ----
  #pragma unroll
  for (int k = t; k < 1024; k += 512) {
    const int c = k >> 9, bi = (k >> 7) & 3, si = k & 127;
    const int lb = (c ? lens_user : lens_item)[bg4 + bi];
    float w = 0.f;
    if (si < lb) w = (c ? tf_user : tf_item)[(bg4 + bi) * SEQ + si];   // lb<=SEQ
    sTF[c][bi][si] = w;
  }

  // ---- B fragments for cluster 0 (32 VGPRs) ----
  bf16x8 breg[2][4];
  #pragma unroll
  for (int nt = 0; nt < 2; ++nt) {
    const int v = v0 + wn * 32 + nt * 16 + l15;
    const unsigned short* pb = wbf + (size_t)v * EDIM + quad * 8;
    const bool ok = (v < VDIM);
    #pragma unroll
    for (int ks = 0; ks < 4; ++ks) {
      bf16x8 z = {0, 0, 0, 0, 0, 0, 0, 0};
      breg[nt][ks] = ok ? *(const bf16x8*)(pb + ks * 32) : z;
    }
  }

  // ---- stage-invariant GEMM LDS base pointers (buffer 0; +ABYTES for buf1) --
  const unsigned char* pA = (const unsigned char*)&sA[0][0];
  const int rowb = (wm * 64 + l15) * 256;
  const unsigned char* aB0 = pA + rowb + (((0 * 4 + quad) ^ l15) << 4);
  const unsigned char* aB1 = pA + rowb + (((1 * 4 + quad) ^ l15) << 4);
  const unsigned char* aB2 = pA + rowb + (((2 * 4 + quad) ^ l15) << 4);
  const unsigned char* aB3 = pA + rowb + (((3 * 4 + quad) ^ l15) << 4);

  // persistent zero C-operand (4 VGPRs) — replaces per-stage acc zero-init
  f32x4 zero4 = {0.f, 0.f, 0.f, 0.f};

  // ---- issue async A DMA for stage 0 into buf0 (tail on light wm1 waves) ---
  {
    const unsigned short* gb = abf + (size_t)bg4 * ATILE;
    #pragma unroll
    for (int i = 0; i < 3; ++i)
      async16(&sA[0][(i * 512 + wave * 64) * 8], gb + (size_t)(i * 512 + t) * 8);
    if (t >= 256)   // waves 4..7 cover shorts 12288..14335
      async16(&sA[0][(1536 + (wave - 4) * 64) * 8], gb + (size_t)(1536 + (t - 256)) * 8);
  }

  #pragma unroll 1
  for (int s = 0; s < 8; ++s) {
    const int cc = s >> 2, it = s & 3, buf = s & 1;

    __syncthreads();   // DMA for buf[s&1] drained; s-1 partials visible;
                       // buf[(s+1)&1] free (its last readers were pre-barrier)

    // ---- issue next stage's DMA into the other buffer (full-stage flight) --
    if (s < 7) {
      const int ns = s + 1;
      unsigned short* db = &sA[ns & 1][0];
      const unsigned short* gb = abf + (size_t)((ns >> 2) * BATCH + bg4 + (ns & 3)) * ATILE;
      #pragma unroll
      for (int i = 0; i < 3; ++i)
        async16(db + (size_t)(i * 512 + wave * 64) * 8, gb + (size_t)(i * 512 + t) * 8);
      if (t >= 256)
        async16(db + (size_t)(1536 + (wave - 4) * 64) * 8, gb + (size_t)(1536 + (t - 256)) * 8);
    }

    // ---- combine previous stage's partials — waves 6-7 (light wm1 side) ----
    if (s > 0 && t >= 384) {
      const int col = t & 127;   // 384..511 -> 0..127
      const int ps = s - 1, pp = ps & 1, pit = ps & 3;
      // EXACT association of the old xor16->pair->combine tree:
      const float den0 = (sDen[pp][0][0][col] + sDen[pp][0][1][col])
                       + (sDen[pp][0][2][col] + sDen[pp][0][3][col]);
      const float den1 = (sDen[pp][1][0][col] + sDen[pp][1][1][col])
                       + (sDen[pp][1][2][col] + sDen[pp][1][3][col]);
      const float num0 = (sNum[pp][0][0][col] + sNum[pp][0][1][col])
                       + (sNum[pp][0][2][col] + sNum[pp][0][3][col]);
      const float num1 = (sNum[pp][1][0][col] + sNum[pp][1][1][col])
                       + (sNum[pp][1][2][col] + sNum[pp][1][3][col]);
      float den = den0 + den1;
      float num = num0 + num1;
      const float dir = sDir[pp][col];
      const float dirE = fexp2(dir * L2E);       // same path as epilogue's den term
      den -= 11.f + dirE;                        // 11 pad rows (101..111) + dir row
      const float val = num * __builtin_amdgcn_rcpf(den) + dir;
      if (ps < 4) sRes[pit][col] = val;
      else {
        const int v = v0 + col;
        if (v < VDIM) out[(size_t)(bg4 + pit) * VDIM + v] = sRes[pit][col] + val;
      }
    }

    // ---- GEMM: 16x16x32 tiles; ks0 seeds from zero4 (no acc init) ----
    f32x4 acc[4][2];
    const int bufB = buf * ABYTES;
    __builtin_amdgcn_s_setprio(1);   // T5: favor MFMA waves over the other
                                     // block's epilogue VALU (anti-phase)
    #pragma unroll
    for (int ks = 0; ks < 4; ++ks) {
      const unsigned char* ab =
          ((ks == 0) ? aB0 : (ks == 1) ? aB1 : (ks == 2) ? aB2 : aB3) + bufB;
      #pragma unroll
      for (int mt = 0; mt < 3; ++mt) {   // JIT af: 4 live regs
        const bf16x8 a = *(const bf16x8*)(ab + mt * 4096);
        if (ks == 0) {
          acc[mt][0] = __builtin_amdgcn_mfma_f32_16x16x32_bf16(a, breg[0][0], zero4, 0, 0, 0);
          acc[mt][1] = __builtin_amdgcn_mfma_f32_16x16x32_bf16(a, breg[1][0], zero4, 0, 0, 0);
        } else {
          acc[mt][0] = __builtin_amdgcn_mfma_f32_16x16x32_bf16(a, breg[0][ks], acc[mt][0], 0, 0, 0);
          acc[mt][1] = __builtin_amdgcn_mfma_f32_16x16x32_bf16(a, breg[1][ks], acc[mt][1], 0, 0, 0);
        }
      }
      if (wm == 0) {   // SGPR-uniform (SCC branch); rows 48..63
        const bf16x8 a3 = *(const bf16x8*)(ab + 3 * 4096);
        if (ks == 0) {
          acc[3][0] = __builtin_amdgcn_mfma_f32_16x16x32_bf16(a3, breg[0][0], zero4, 0, 0, 0);
          acc[3][1] = __builtin_amdgcn_mfma_f32_16x16x32_bf16(a3, breg[1][0], zero4, 0, 0, 0);
        } else {
          acc[3][0] = __builtin_amdgcn_mfma_f32_16x16x32_bf16(a3, breg[0][ks], acc[3][0], 0, 0, 0);
          acc[3][1] = __builtin_amdgcn_mfma_f32_16x16x32_bf16(a3, breg[1][ks], acc[3][1], 0, 0, 0);
        }
      }
    }
    __builtin_amdgcn_s_setprio(0);

    // reload B for cluster 1 once (covered by epilogue; drained at next sync)
    if (s == 3) {
      const unsigned short* wb1 = wbf + (size_t)VDIM * EDIM;
      #pragma unroll
      for (int nt = 0; nt < 2; ++nt) {
        const int v = v0 + wn * 32 + nt * 16 + l15;
        const unsigned short* pb = wb1 + (size_t)v * EDIM + quad * 8;
        const bool ok = (v < VDIM);
        #pragma unroll
        for (int ks = 0; ks < 4; ++ks) {
          bf16x8 z = {0, 0, 0, 0, 0, 0, 0, 0};
          breg[nt][ks] = ok ? *(const bf16x8*)(pb + ks * 32) : z;
        }
      }
    }

    // ---- epilogue: packed-f32 softmax partials (identical math to R5) ----
    f32x2 wlo[4], whi[4];
    #pragma unroll
    for (int mt = 0; mt < 4; ++mt) {
      const int row0 = wm * 64 + mt * 16 + quad * 4;   // <=124 < 128, pad region is 0
      const f32x4 w4 = *(const f32x4*)&sTF[cc][it][row0];
      f32x2 a = {w4[0], w4[1]}; f32x2 b = {w4[2], w4[3]};
      wlo[mt] = a; whi[mt] = b;
    }

    #pragma unroll
    for (int nt = 0; nt < 2; ++nt) {
      f32x2 den2 = {0.f, 0.f}, num2 = {0.f, 0.f};

      #define EPAIRS(MT)                                                  \
      {                                                                   \
        const f32x4 a4 = acc[MT][nt];                                     \
        const f32x2 vlo = {a4[0], a4[1]};                                 \
        const f32x2 vhi = {a4[2], a4[3]};                                 \
        const f32x2 mlo = pk_mul(vlo, L2E2);                              \
        const f32x2 mhi = pk_mul(vhi, L2E2);                              \
        f32x2 elo, ehi;                                                   \
        elo[0] = fexp2(mlo[0]); elo[1] = fexp2(mlo[1]);                   \
        ehi[0] = fexp2(mhi[0]); ehi[1] = fexp2(mhi[1]);                   \
        pk_add_acc(den2, elo);                                            \
        pk_add_acc(den2, ehi);                                            \
        pk_fma_acc(num2, wlo[MT], pk_mul(elo, vlo));                      \
        pk_fma_acc(num2, whi[MT], pk_mul(ehi, vhi));                      \
      }
      EPAIRS(0)
      EPAIRS(1)
      EPAIRS(2)
      if (wm == 0) EPAIRS(3)   // SGPR-uniform; static acc[3][nt]
      #undef EPAIRS

      // per-lane partial P(quad) — NO shuffles; combine does the exact tree
      const float den = den2[0] + den2[1];
      const float num = num2[0] + num2[1];
      const int col = wn * 32 + nt * 16 + l15;
      sDen[buf][wm][quad][col] = den;
      sNum[buf][wm][quad][col] = num;
      // row 100 = wm1, mt2, quad1, r0
      if (wm == 1 && quad == 1) sDir[buf][col] = acc[2][nt][0];
    }
  }

  __syncthreads();

  // ---- combine final stage (ps=7, parity 1, it=3) — waves 6-7 ----
  if (t >= 384) {
    const int col = t & 127;
    const float den0 = (sDen[1][0][0][col] + sDen[1][0][1][col])
                     + (sDen[1][0][2][col] + sDen[1][0][3][col]);
    const float den1 = (sDen[1][1][0][col] + sDen[1][1][1][col])
                     + (sDen[1][1][2][col] + sDen[1][1][3][col]);
    const float num0 = (sNum[1][0][0][col] + sNum[1][0][1][col])
                     + (sNum[1][0][2][col] + sNum[1][0][3][col]);
    const float num1 = (sNum[1][1][0][col] + sNum[1][1][1][col])
                     + (sNum[1][1][2][col] + sNum[1][1][3][col]);
    float den = den0 + den1;
    float num = num0 + num1;
    const float dir = sDir[1][col];
    const float dirE = fexp2(dir * L2E);
    den -= 11.f + dirE;
    const float val = num * __builtin_amdgcn_rcpf(den) + dir;
    const int v = v0 + col;
    if (v < VDIM) out[(size_t)(bg4 + 3) * VDIM + v] = sRes[3][col] + val;
  }
}

extern "C" void kernel_launch(void* const* d_in, const int* in_sizes, int n_in,
                              void* d_out, int out_size, void* d_ws, size_t ws_size,
                              hipStream_t stream) {
  const int*   attr_item = (const int*)d_in[0];
  const float* tf_item   = (const float*)d_in[1];
  const int*   lens_item = (const int*)d_in[2];
  const int*   item_ids  = (const int*)d_in[3];
  const int*   attr_user = (const int*)d_in[4];
  const float* tf_user   = (const float*)d_in[5];
  const int*   lens_user = (const int*)d_in[6];
  const int*   user_ids  = (const int*)d_in[7];
  const float* W_item    = (const float*)d_in[8];
  const float* W_user    = (const float*)d_in[9];
  const float* user_emb  = (const float*)d_in[10];
  const float* item_emb  = (const float*)d_in[11];
  float* out = (float*)d_out;

  unsigned short* wbf = (unsigned short*)d_ws;                  // [2][V][E] bf16 (linear)
  unsigned short* abf = wbf + (size_t)2 * VDIM * EDIM;          // [2][64] swizzled 28KB tiles

  prep_kernel<<<dim3(2500 + 128), 256, 0, stream>>>(W_item, W_user, attr_item, attr_user,
                                                    item_ids, user_ids, item_emb, user_emb,
                                                    wbf, abf);
  main_kernel<<<dim3(GRID), 512, 0, stream>>>(wbf, abf, tf_item, lens_item,
                                              tf_user, lens_user, out);
}